// Round 11
// baseline (219.257 us; speedup 1.0000x reference)
//
#include <hip/hip_runtime.h>

// Problem constants
#define NBATCH  4
#define TSEQ    2048
#define MROWS   8192
#define NCAT    1280              // 512 (a_b|a_t) + 512 (c_b|c_t) + 256 (z_t)
#define NE      512

// ---- workspace layout (float offsets) ----
#define OFF_WQT   0u                          // Wq^T bf16 [1024][1024]
#define OFF_WKT   524288u                     // Wk^T bf16 [1024][1024]
#define OFF_WOB   1048576u                    // Wo   bf16 [1024][1024]
#define OFF_VCT   1572864u                    // Vc^T bf16 [512][1024]
#define OFF_WCT   1835008u                    // Wc^T bf16 [512][1024]
#define OFF_UCT   2097152u                    // Uc^T bf16 [512][1024]
#define OFF_B2    2359296u                    // [1024] f32
#define OFF_PB    2360320u                    // PcatT bf16 [1280][1024]
#define OFF_GB    3015680u                    // G bf16 [1024][512]
#define OFF_Y     3277824u                    // Y bf16 [8192][1280]
#define OFF_SCR   13763584u                   // f32 [4][32][768] raw seg sums
#define OFF_XB    13861888u                   // x bf16 [8192][1024]
#define OFF_EB    OFF_XB                      // E bf16 [8192][512] (aliases xb)

typedef __attribute__((ext_vector_type(8))) short bf16x8;
typedef __attribute__((ext_vector_type(4))) float f32x4;

__device__ __forceinline__ unsigned short f2bf(float f) {
  union { float f; unsigned u; } v; v.f = f;
  return (unsigned short)((v.u + 0x7fff + ((v.u >> 16) & 1)) >> 16);  // RNE
}
__device__ __forceinline__ float bf2f(unsigned short u) {
  union { unsigned u; float f; } v; v.u = ((unsigned)u) << 16;
  return v.f;
}

__device__ __forceinline__ void gload16(const void* g, void* l) {
  __builtin_amdgcn_global_load_lds(
      (const __attribute__((address_space(1))) unsigned*)g,
      (__attribute__((address_space(3))) unsigned*)l, 16, 0, 0);
}

// XCD-aware bijective swizzle of the linearized block id (nwg % 8 == 0).
__device__ __forceinline__ void xcd_swizzle(int& bx, int& by) {
  const int gx = gridDim.x;
  const int nwg = gx * gridDim.y;
  const int n = by * gx + bx;
  const int q = nwg >> 3;
  const int s = (n & 7) * q + (n >> 3);
  bx = s % gx; by = s / gx;
}

// ========================= 8-phase 256x256 NT GEMM ===========================
// C[m0:+256][n0:+256] = A[M][K]*B[N][K]^T. 512 thr = 8 waves (2M x 4N).
// Wave output 128x64, as 4 quadrants (mh,nh) of 64x32. BK=64, 2 K-tile LDS
// buffers (A 256x64 + B 256x64 bf16 per tile = 64KB; total 128KB).
// Half-tiles per K-tile: ht0=A rows0-127, ht1=B rows0-127, ht2=A rows128-255,
// ht3=B rows128-255 (each = 2 gload_lds/thread). During tile t's 4 phases we
// stage tile t+1's ht p into buf d^1.
// Wait proof (FIFO vmcnt, 2 loads/ht, per-wave; barrier = cross-wave seal):
//  phase p0(t) vmcnt(4): outstanding {A1(t),B1(t),A0(t+1)} -> <=4 leaves
//   {B1(t),A0(t+1)} => A1(t) retired before p0's barrier => p1's read safe.
//  p1(t) vmcnt(4): {B1(t),A0+,B0+} -> leaves {A0+,B0+} => B1(t) retired => p2 ok.
//  p2(t) vmcnt(4): {A0+,B0+,A1+} -> leaves {B0+,A1+} => A0(t+1) retired => p0(t+1) ok.
//  p3(t) vmcnt(4): {B0+,A1+,B1+} -> leaves {A1+,B1+} => B0(t+1) retired => p0/p1(t+1) ok.
//  Last tile (no staging): p0 vmcnt(2) retires A1, p1 vmcnt(0) retires B1.
//  WAR: reads of buf d^1 complete (compiler lgkm before MFMA) before tile t-1's
//  trailing barrier; stages into d^1 issue after it.
// LDS chunk swizzle (round-6-proven, 0 conflicts): row r, chunk c (8x16B/row):
// LDS[c] = global[c ^ (r&7)] via pre-swizzled source (gload dest lane-linear);
// ds_read XORs the same involution.
// EPI: C = acc / ((m & 2047)+1) + bias[n].  OBF: C is bf16.
// CS: cols>=512 write 64-row column sums to scr[b][seg][col-512].
// K-accumulation order identical to the 128^2 BK=64 kernel -> bit-identical.
template <int EPI, int OBF, int CS>
__global__ __launch_bounds__(512, 2) void mfma_nt256(
    const short* __restrict__ A, const short* __restrict__ B,
    void* __restrict__ Cv, int K, int ldA, int ldB, int ldC,
    const float* __restrict__ bias, float* __restrict__ scr) {
  __shared__ short L[65536];            // 128 KB
  int bx = blockIdx.x, by = blockIdx.y;
  xcd_swizzle(bx, by);
  const int m0 = by * 256, n0 = bx * 256;
  const int tid = threadIdx.x;
  const int l = tid & 63;
  const int wm2 = (tid >> 6) >> 2;      // 0..1 -> 64-row sub-band
  const int wn4 = (tid >> 6) & 3;       // 0..3 -> 32-col sub-band
  const int s_r = tid >> 3;             // staging row 0..63
  const int s_c = tid & 7;              // staging chunk 0..7
  const int fr = l & 15;
  const int kq = l >> 4;                // 0..3

  f32x4 acc[2][2][4][2] = {};           // [mh][nh][mf][nf]
  const int nt = K >> 6;

#define STAGE_HT(kt, ht, d) do {                                             \
    const int mat_ = (ht) & 1;                                               \
    const int hf_ = (ht) >> 1;                                               \
    short* dst_ = L + (d) * 32768 + mat_ * 16384 + hf_ * 8192;               \
    const short* gs_ = mat_ ? B : A;                                         \
    const int gb_ = mat_ ? n0 : m0;                                          \
    const int ld_ = mat_ ? ldB : ldA;                                        \
    _Pragma("unroll")                                                        \
    for (int j_ = 0; j_ < 2; ++j_) {                                         \
      const int rl_ = j_ * 64 + s_r;                                         \
      const int rg_ = hf_ * 128 + rl_;                                       \
      const int sw_ = (s_c ^ (rg_ & 7)) * 8;                                 \
      gload16(gs_ + (size_t)(gb_ + rg_) * ld_ + (kt) * 64 + sw_,             \
              dst_ + rl_ * 64 + s_c * 8);                                    \
    }                                                                        \
  } while (0)

#define PHASE(t, p, mh, nh, TAILW) do {                                      \
    const int d_ = (t) & 1;                                                  \
    const short* As_ = L + d_ * 32768;                                       \
    const short* Bs_ = As_ + 16384;                                          \
    bf16x8 af_[4][2], bv_[2][2];                                             \
    _Pragma("unroll")                                                        \
    for (int mf_ = 0; mf_ < 4; ++mf_) {                                      \
      const int ra_ = (mh) * 128 + wm2 * 64 + mf_ * 16 + fr;                 \
      _Pragma("unroll")                                                      \
      for (int kk_ = 0; kk_ < 2; ++kk_) {                                    \
        const int q_ = kk_ * 4 + kq;                                         \
        af_[mf_][kk_] = *(const bf16x8*)&As_[ra_ * 64 + ((q_ ^ (ra_ & 7)) * 8)]; \
      }                                                                      \
    }                                                                        \
    _Pragma("unroll")                                                        \
    for (int nf_ = 0; nf_ < 2; ++nf_) {                                      \
      const int rb_ = (nh) * 128 + wn4 * 32 + nf_ * 16 + fr;                 \
      _Pragma("unroll")                                                      \
      for (int kk_ = 0; kk_ < 2; ++kk_) {                                    \
        const int q_ = kk_ * 4 + kq;                                         \
        bv_[nf_][kk_] = *(const bf16x8*)&Bs_[rb_ * 64 + ((q_ ^ (rb_ & 7)) * 8)]; \
      }                                                                      \
    }                                                                        \
    if ((t) + 1 < nt) {                                                      \
      STAGE_HT((t) + 1, p, d_ ^ 1);                                          \
      asm volatile("s_waitcnt vmcnt(4)" ::: "memory");                       \
    } else {                                                                 \
      TAILW;                                                                 \
    }                                                                        \
    __builtin_amdgcn_s_barrier();                                            \
    __builtin_amdgcn_s_setprio(1);                                           \
    _Pragma("unroll")                                                        \
    for (int kk_ = 0; kk_ < 2; ++kk_)                                        \
      _Pragma("unroll")                                                      \
      for (int mf_ = 0; mf_ < 4; ++mf_)                                      \
        _Pragma("unroll")                                                    \
        for (int nf_ = 0; nf_ < 2; ++nf_)                                    \
          acc[mh][nh][mf_][nf_] = __builtin_amdgcn_mfma_f32_16x16x32_bf16(   \
              af_[mf_][kk_], bv_[nf_][kk_], acc[mh][nh][mf_][nf_], 0, 0, 0); \
    __builtin_amdgcn_s_setprio(0);                                           \
    __builtin_amdgcn_s_barrier();                                            \
  } while (0)

  // prologue: stage tile 0's 4 half-tiles; A0,B0 landed; A1,B1 may fly
  STAGE_HT(0, 0, 0); STAGE_HT(0, 1, 0); STAGE_HT(0, 2, 0); STAGE_HT(0, 3, 0);
  asm volatile("s_waitcnt vmcnt(4)" ::: "memory");
  __builtin_amdgcn_s_barrier();

  for (int t = 0; t < nt; ++t) {
    PHASE(t, 0, 0, 0, asm volatile("s_waitcnt vmcnt(2)" ::: "memory"));
    PHASE(t, 1, 1, 0, asm volatile("s_waitcnt vmcnt(0)" ::: "memory"));
    PHASE(t, 2, 0, 1, (void)0);
    PHASE(t, 3, 1, 1, (void)0);
  }
#undef STAGE_HT
#undef PHASE

  // epilogue. C/D layout: col = l&15, row = (l>>4)*4 + j
#pragma unroll
  for (int mh = 0; mh < 2; ++mh)
#pragma unroll
    for (int nh = 0; nh < 2; ++nh) {
#pragma unroll
      for (int mf = 0; mf < 4; ++mf)
#pragma unroll
        for (int j = 0; j < 4; ++j) {
          const int gm = m0 + mh * 128 + wm2 * 64 + mf * 16 + (l >> 4) * 4 + j;
          float inv = 1.0f;
          if (EPI) inv = 1.0f / (float)((gm & (TSEQ - 1)) + 1);
#pragma unroll
          for (int nf = 0; nf < 2; ++nf) {
            const int gn = n0 + nh * 128 + wn4 * 32 + nf * 16 + (l & 15);
            float v = acc[mh][nh][mf][nf][j];
            if (EPI) v = v * inv + bias[gn];
            if (OBF) ((short*)Cv)[(size_t)gm * ldC + gn] = (short)f2bf(v);
            else     ((float*)Cv)[(size_t)gm * ldC + gn] = v;
          }
        }
      if (CS) {
        const int rowband = m0 + mh * 128 + wm2 * 64;
        const int bb = rowband >> 11;
        const int seg = (rowband >> 6) & 31;
#pragma unroll
        for (int nf = 0; nf < 2; ++nf) {
          const int gc0 = n0 + nh * 128 + wn4 * 32 + nf * 16;
          if (gc0 >= 512) {
            float s = 0.f;
#pragma unroll
            for (int mf = 0; mf < 4; ++mf)
#pragma unroll
              for (int j = 0; j < 4; ++j) s += acc[mh][nh][mf][nf][j];
            s += __shfl_xor(s, 16, 64);
            s += __shfl_xor(s, 32, 64);
            if (l < 16)
              scr[(size_t)(bb * 32 + seg) * 768 + (gc0 + l - 512)] = s;
          }
        }
      }
    }
}

// ===== 128^2 tile (round-10 proven) — used for the small prep GEMMs ==========
template <int OBF>
__device__ __forceinline__ void mfma_tile(
    const short* __restrict__ A, const short* __restrict__ B, void* __restrict__ Cv,
    int K, int ldA, int ldB, int ldC, int m0, int n0, short* L) {
  const int tid = threadIdx.x;
  const int l = tid & 63;
  const int wv = tid >> 6;
  const int wm = (wv >> 1) * 64, wn = (wv & 1) * 64;
  const int srow = tid >> 3;
  const int schk = tid & 7;
  const int arow = wm + (l & 15), brow = wn + (l & 15);
  const int kq = l >> 4;

  f32x4 acc[4][4] = {};

#define STAGE(k0, buf) do {                                                  \
    short* As_ = L + (buf) * 16384;                                          \
    short* Bs_ = As_ + 8192;                                                 \
    _Pragma("unroll")                                                        \
    for (int p = 0; p < 4; ++p) {                                            \
      const int r = p * 32 + srow;                                           \
      const int sw = (schk ^ (r & 7)) * 8;                                   \
      gload16(A + (size_t)(m0 + r) * ldA + (k0) + sw, As_ + r * 64 + schk * 8); \
      gload16(B + (size_t)(n0 + r) * ldB + (k0) + sw, Bs_ + r * 64 + schk * 8); \
    }                                                                        \
  } while (0)

#define COMPUTE(buf) do {                                                    \
    short* As_ = L + (buf) * 16384;                                          \
    short* Bs_ = As_ + 8192;                                                 \
    _Pragma("unroll")                                                        \
    for (int h = 0; h < 2; ++h) {                                            \
      bf16x8 af[4], bfr[4];                                                  \
      _Pragma("unroll")                                                      \
      for (int m = 0; m < 4; ++m) {                                          \
        const int r = arow + m * 16;                                         \
        af[m] = *(const bf16x8*)&As_[r * 64 + (((h * 4 + kq) ^ (r & 7)) * 8)]; \
      }                                                                      \
      _Pragma("unroll")                                                      \
      for (int n = 0; n < 4; ++n) {                                          \
        const int r = brow + n * 16;                                         \
        bfr[n] = *(const bf16x8*)&Bs_[r * 64 + (((h * 4 + kq) ^ (r & 7)) * 8)]; \
      }                                                                      \
      _Pragma("unroll")                                                      \
      for (int m = 0; m < 4; ++m)                                            \
        _Pragma("unroll")                                                    \
        for (int n = 0; n < 4; ++n)                                          \
          acc[m][n] = __builtin_amdgcn_mfma_f32_16x16x32_bf16(af[m], bfr[n], acc[m][n], 0, 0, 0); \
    }                                                                        \
  } while (0)

  STAGE(0, 0);
  const int nt = K >> 6;
  for (int t = 0; t < nt; ++t) {
    if (t + 1 < nt) {
      STAGE((t + 1) << 6, (t + 1) & 1);
      asm volatile("s_waitcnt vmcnt(8)" ::: "memory");
    } else {
      asm volatile("s_waitcnt vmcnt(0)" ::: "memory");
    }
    asm volatile("s_barrier" ::: "memory");
    COMPUTE(t & 1);
    asm volatile("s_barrier" ::: "memory");
  }
#undef STAGE
#undef COMPUTE

  const int cc = wn + (l & 15);
  const int crb = wm + (l >> 4) * 4;
#pragma unroll
  for (int m = 0; m < 4; ++m) {
#pragma unroll
    for (int j = 0; j < 4; ++j) {
      const int gm = m0 + crb + m * 16 + j;
#pragma unroll
      for (int n = 0; n < 4; ++n) {
        const int gn = n0 + cc + n * 16;
        float v = acc[m][n][j];
        if (OBF) ((short*)Cv)[(size_t)gm * ldC + gn] = (short)f2bf(v);
        else     ((float*)Cv)[(size_t)gm * ldC + gn] = v;
      }
    }
  }
}

// prep2: blocks 0..95 = 3 prep GEMMs x 32 tiles (K=1024, bf16 out);
// blocks 96..8287 = f2b(x).
__global__ __launch_bounds__(256) void prep2(
    const short* __restrict__ VCT, const short* __restrict__ WQT,
    const short* __restrict__ WCT, const short* __restrict__ WKT,
    const short* __restrict__ WOB, const short* __restrict__ UCT,
    short* __restrict__ Pb, short* __restrict__ Gb,
    const float* __restrict__ x, short* __restrict__ xb) {
  __shared__ short L[32768];
  const int bid = blockIdx.x;
  if (bid >= 96) {
    const size_t j = ((size_t)(bid - 96) * 256 + threadIdx.x) * 4;
    const float4 v = *(const float4*)&x[j];
    ushort4 o;
    o.x = f2bf(v.x); o.y = f2bf(v.y); o.z = f2bf(v.z); o.w = f2bf(v.w);
    *(ushort4*)&((unsigned short*)xb)[j] = o;
    return;
  }
  const int g = bid >> 5, t = bid & 31;
  if (g == 0)
    mfma_tile<1>(VCT, WQT, Pb, 1024, 1024, 1024, 1024,
                 (t >> 3) * 128, (t & 7) * 128, L);
  else if (g == 1)
    mfma_tile<1>(WCT, WKT, Pb + (size_t)512 * 1024, 1024, 1024, 1024, 1024,
                 (t >> 3) * 128, (t & 7) * 128, L);
  else
    mfma_tile<1>(WOB, UCT, Gb, 1024, 1024, 1024, 512,
                 (t >> 2) * 128, (t & 3) * 128, L);
}

// ===== prep_all: transposes + f2b(Wo) + bias_proj, one launch ================
__global__ __launch_bounds__(256) void prep_all(
    const float* __restrict__ Vb, const float* __restrict__ Vt,
    const float* __restrict__ Wb, const float* __restrict__ Wt,
    const float* __restrict__ Ub, const float* __restrict__ Ut,
    const float* __restrict__ Xt, const float* __restrict__ Wq,
    const float* __restrict__ Wk, const float* __restrict__ Wo,
    const float* __restrict__ bias_b, const float* __restrict__ bias_t,
    const float* __restrict__ alpha_p,
    short* __restrict__ VCT, short* __restrict__ WCT, short* __restrict__ UCT,
    short* __restrict__ PbXt, short* __restrict__ WQT, short* __restrict__ WKT,
    short* __restrict__ WOB, float* __restrict__ b2) {
  const int bid = blockIdx.x;
  const int tid = threadIdx.x;
  if (bid >= 1984) {                        // bias_proj: d = bid - 1984
    const float al = *alpha_p;
    const int d = bid - 1984;
    float s = 0.f;
    for (int e = tid; e < 1024; e += 256)
      s += Wo[(size_t)d * 1024 + e] * (bias_b[e] + al * bias_t[e]);
    __shared__ float red[256];
    red[tid] = s; __syncthreads();
    for (int off = 128; off > 0; off >>= 1) {
      if (tid < off) red[tid] += red[tid + off];
      __syncthreads();
    }
    if (tid == 0) b2[d] = red[0];
    return;
  }
  if (bid >= 960) {                         // f2b: Wo (1M floats)
    const size_t j = ((size_t)(bid - 960) * 256 + tid) * 4;
    const float4 v = *(const float4*)&Wo[j];
    ushort4 o;
    o.x = f2bf(v.x); o.y = f2bf(v.y); o.z = f2bf(v.z); o.w = f2bf(v.w);
    *(ushort4*)&((unsigned short*)WOB)[j] = o;
    return;
  }
  const float* src; short* O; int r0, d0, c0, ldS;
  if (bid < 384) {
    const int z = bid >> 7, t = bid & 127;
    r0 = (t >> 4) * 64; d0 = (t & 15) * 64; ldS = 256;
    const float* S0 = z == 0 ? Vb : z == 1 ? Wb : Ub;
    const float* S1 = z == 0 ? Vt : z == 1 ? Wt : Ut;
    O = z == 0 ? VCT : z == 1 ? WCT : UCT;
    src = (r0 < 256) ? S0 : S1; c0 = r0 & 255;
  } else if (bid < 448) {
    const int t = bid - 384;
    r0 = (t >> 4) * 64; d0 = (t & 15) * 64; ldS = 256;
    src = Xt; c0 = r0; O = PbXt;
  } else {
    const int t = bid - 448;
    const int w = t >> 8, tt = t & 255;
    r0 = (tt >> 4) * 64; d0 = (tt & 15) * 64; ldS = 1024;
    src = w ? Wk : Wq; O = w ? WKT : WQT; c0 = r0;
  }
  __shared__ float Ts[64][65];
  const int lr = tid >> 4;
  const int lc = (tid & 15) * 4;
#pragma unroll
  for (int p = 0; p < 4; ++p) {
    const int row = lr + p * 16;
    const float4 v = *(const float4*)&src[(size_t)(d0 + row) * ldS + c0 + lc];
    Ts[row][lc + 0] = v.x; Ts[row][lc + 1] = v.y;
    Ts[row][lc + 2] = v.z; Ts[row][lc + 3] = v.w;
  }
  __syncthreads();
#pragma unroll
  for (int p = 0; p < 4; ++p) {
    const int ri = lr + p * 16;
    ushort4 o;
    o.x = f2bf(Ts[lc + 0][ri]); o.y = f2bf(Ts[lc + 1][ri]);
    o.z = f2bf(Ts[lc + 2][ri]); o.w = f2bf(Ts[lc + 3][ri]);
    *(ushort4*)&((unsigned short*)O)[(size_t)(r0 + ri) * 1024 + d0 + lc] = o;
  }
}

// ===== fused scan: self-prefix + stage-3 + combine -> Eb, depth-8 prefetch ====
#define LOADR(s, t) {                                                   \
    const unsigned short* p_ = yb + (size_t)(t) * NCAT;                 \
    ab##s = bf2f(p_[c2]);        at##s = bf2f(p_[256 + c2]);            \
    cb##s = bf2f(p_[512 + c2]);  ct##s = bf2f(p_[768 + c2]);            \
    zt##s = bf2f(p_[1024 + c2]); }
#define STEPR(s, t) {                                                   \
    run_cb += cb##s; run_ct += ct##s; run_zt += zt##s;                  \
    const float inv_ = 1.0f / (float)(segbase + (t) + 1);               \
    unsigned short* er_ = Eb + (row0 + (t)) * 512;                      \
    er_[c2]       = f2bf(ab##s * run_cb);                               \
    er_[256 + c2] = f2bf(al * at##s * (run_zt * inv_) * run_ct); }
__global__ __launch_bounds__(256) void scan_combine(
    const unsigned short* __restrict__ Y, const float* __restrict__ scr,
    unsigned short* __restrict__ Eb, const float* __restrict__ alpha_p) {
  const float al = *alpha_p;
  const int c2 = threadIdx.x;
  const int seg = blockIdx.x, b = blockIdx.y;
  const int segbase = seg * 64;
  float run_cb = 0.f, run_ct = 0.f, run_zt = 0.f;
  for (int s = 0; s < seg; ++s) {
    const float* sr = scr + (size_t)(b * 32 + s) * 768;
    run_cb += sr[c2]; run_ct += sr[256 + c2]; run_zt += sr[512 + c2];
  }
  const size_t row0 = (size_t)(b * TSEQ + segbase);
  const unsigned short* yb = Y + row0 * NCAT;
  float ab0, at0, cb0, ct0, zt0, ab1, at1, cb1, ct1, zt1;
  float ab2, at2, cb2, ct2, zt2, ab3, at3, cb3, ct3, zt3;
  float ab4, at4, cb4, ct4, zt4, ab5, at5, cb5, ct5, zt5;
  float ab6, at6, cb6, ct6, zt6, ab7, at7, cb7, ct7, zt7;
  LOADR(0, 0) LOADR(1, 1) LOADR(2, 2) LOADR(3, 3)
  LOADR(4, 4) LOADR(5, 5) LOADR(6, 6) LOADR(7, 7)
  for (int t = 0; t < 64; t += 8) {
    STEPR(0, t + 0) if (t + 8 < 64)  LOADR(0, t + 8)
    STEPR(1, t + 1) if (t + 9 < 64)  LOADR(1, t + 9)
    STEPR(2, t + 2) if (t + 10 < 64) LOADR(2, t + 10)
    STEPR(3, t + 3) if (t + 11 < 64) LOADR(3, t + 11)
    STEPR(4, t + 4) if (t + 12 < 64) LOADR(4, t + 12)
    STEPR(5, t + 5) if (t + 13 < 64) LOADR(5, t + 13)
    STEPR(6, t + 6) if (t + 14 < 64) LOADR(6, t + 14)
    STEPR(7, t + 7) if (t + 15 < 64) LOADR(7, t + 15)
  }
}
#undef LOADR
#undef STEPR

// ================= launch =================
extern "C" void kernel_launch(void* const* d_in, const int* in_sizes, int n_in,
                              void* d_out, int out_size, void* d_ws, size_t ws_size,
                              hipStream_t stream) {
  const float* x      = (const float*)d_in[0];
  const float* Wq     = (const float*)d_in[1];
  const float* Wk     = (const float*)d_in[2];
  const float* Wo     = (const float*)d_in[3];
  const float* Ub     = (const float*)d_in[4];
  const float* Vb     = (const float*)d_in[5];
  const float* Wb     = (const float*)d_in[6];
  const float* bias_b = (const float*)d_in[7];
  const float* Ut     = (const float*)d_in[8];
  const float* Vt     = (const float*)d_in[9];
  const float* Wt     = (const float*)d_in[10];
  const float* Xt     = (const float*)d_in[11];
  const float* bias_t = (const float*)d_in[12];
  const float* alpha  = (const float*)d_in[13];
  float* out = (float*)d_out;
  float* ws  = (float*)d_ws;

  short* WQT = (short*)(ws + OFF_WQT);
  short* WKT = (short*)(ws + OFF_WKT);
  short* WOB = (short*)(ws + OFF_WOB);
  short* VCT = (short*)(ws + OFF_VCT);
  short* WCT = (short*)(ws + OFF_WCT);
  short* UCT = (short*)(ws + OFF_UCT);
  float* b2  = ws + OFF_B2;
  short* Pb  = (short*)(ws + OFF_PB);
  short* Gb  = (short*)(ws + OFF_GB);
  unsigned short* Yb = (unsigned short*)(ws + OFF_Y);
  float* scr = ws + OFF_SCR;
  short* xb  = (short*)(ws + OFF_XB);
  short* Eb  = (short*)(ws + OFF_EB);

  // 1. transposes + f2b(Wo) + bias projection
  prep_all<<<3008, 256, 0, stream>>>(Vb, Vt, Wb, Wt, Ub, Ut, Xt, Wq, Wk, Wo,
                                     bias_b, bias_t, alpha,
                                     VCT, WCT, UCT, Pb + (size_t)1024 * 1024,
                                     WQT, WKT, WOB, b2);
  // 2. prep GEMMs (96 blocks) + f2b(x) (8192 blocks)
  prep2<<<8288, 256, 0, stream>>>(VCT, WQT, WCT, WKT, WOB, UCT, Pb, Gb, x, xb);
  // 3. Y(bf16) = xb @ Pb^T (M=8192,N=1280,K=1024), 8-phase 256^2 + col sums
  mfma_nt256<0, 1, 1><<<dim3(NCAT / 256, MROWS / 256), 512, 0, stream>>>(
      xb, Pb, Yb, 1024, 1024, 1024, NCAT, nullptr, scr);
  // 4. fused prefix + scan + combine -> Eb
  scan_combine<<<dim3(32, NBATCH), 256, 0, stream>>>(Yb, scr, (unsigned short*)Eb, alpha);
  // 5. out = diag(1/counts) * (Eb @ Gb^T) + b2, 8-phase 256^2 (K=512)
  mfma_nt256<1, 0, 0><<<dim3(1024 / 256, MROWS / 256), 512, 0, stream>>>(
      Eb, Gb, out, 512, 512, 512, 1024, b2, nullptr);
}